// Round 3
// baseline (824.320 us; speedup 1.0000x reference)
//
#include <hip/hip_runtime.h>
#include <math.h>

#define S_LEN 512
#define D_IN  768
#define H_DIM 50
#define G4    200
#define NPAD  208      // 13 * 16
#define NCT   13
#define BROWS 128
#define NTILES 1024    // (256*512)/128
#define KSTEPS 24      // 768/32

typedef float f32x4 __attribute__((ext_vector_type(4)));
typedef short s16x8 __attribute__((ext_vector_type(8)));

__device__ ushort g_Wh[NPAD * D_IN];
__device__ ushort g_Wl[NPAD * D_IN];
__device__ int    g_counter;

__device__ __forceinline__ float fsigmoid(float x) {
    return 1.0f / (1.0f + __expf(-x));
}
__device__ __forceinline__ float ftanh(float x) {
    float ax = fabsf(x);
    float e  = __expf(-2.0f * ax);
    float t  = (1.0f - e) / (1.0f + e);
    return copysignf(t, x);
}

// ---------------------------------------------------------------------------
// Prelude: split W_ih into bf16 hi/lo (truncation; hi+lo carries ~16 mantissa
// bits -> split-bf16 GEMM rel err ~2^-16). Pads cols 200..207 with zeros.
// Also resets the work-queue counter (runs before gemm every launch).
// ---------------------------------------------------------------------------
__global__ void prep_w(const float* __restrict__ W) {
    int idx = blockIdx.x * 256 + threadIdx.x;
    if (idx == 0) g_counter = 0;
    if (idx >= NPAD * D_IN) return;
    int n = idx / D_IN, k = idx - n * D_IN;
    float v = (n < G4) ? W[n * D_IN + k] : 0.f;
    unsigned u = __float_as_uint(v);
    ushort hi = (ushort)(u >> 16);
    float  hv = __uint_as_float((unsigned)hi << 16);
    float  d  = v - hv;
    g_Wh[idx] = hi;
    g_Wl[idx] = (ushort)(__float_as_uint(d) >> 16);
}

// pack two floats' bf16-truncations (hi) and residual bf16s (lo) into u32s
__device__ __forceinline__ void pack2(float f0, float f1, unsigned& h, unsigned& l) {
    unsigned u0 = __float_as_uint(f0), u1 = __float_as_uint(f1);
    h = (u0 >> 16) | (u1 & 0xffff0000u);
    float d0 = f0 - __uint_as_float(u0 & 0xffff0000u);
    float d1 = f1 - __uint_as_float(u1 & 0xffff0000u);
    l = (__float_as_uint(d0) >> 16) | (__float_as_uint(d1) & 0xffff0000u);
}

// ---------------------------------------------------------------------------
// Kernel 1: xg = x @ W_ih^T via 16x16x32 bf16 MFMA, split-precision
// (AhBh + AlBh + AhBl). No LDS: A-frags are 8 consecutive k of one row ->
// direct coalesced global loads + in-reg split; B-frags from L2-resident
// g_Wh/g_Wl. Persistent blocks on an atomic queue; 128-row tiles; waves skip
// their 32-row strip when fully masked (mask monotone in t).
// Wave layout: wave w owns rows r0=tile*128+w*32 (2 row-tiles of 16),
// all 13 col-tiles. A-frag: lane holds x[r0+(lane&15)][k0+(lane>>4)*8+j].
// C-frag (m89-verified): col=lane&15, row=(lane>>4)*4+reg.
// ---------------------------------------------------------------------------
__global__ __launch_bounds__(256, 2) void gemm_xg(
    const float* __restrict__ x, const int* __restrict__ mask,
    float* __restrict__ xg)
{
    __shared__ int tile_sh;
    const int tid  = threadIdx.x;
    const int wv   = tid >> 6;
    const int lane = tid & 63;
    const int lr   = lane & 15;          // row (A) / col (B) within 16-tile
    const int kch  = (lane >> 4) * 8;    // k-chunk within 32-step

    for (;;) {
        if (tid == 0) tile_sh = atomicAdd(&g_counter, 1);
        __syncthreads();
        const int tile = tile_sh;
        __syncthreads();
        if (tile >= NTILES) return;

        const int row0 = tile * BROWS;
        const int b    = row0 >> 9;
        const int t0   = row0 & (S_LEN - 1);
        // wave-level skip: this wave's 32-row strip entirely past length[b]?
        if (mask[b * S_LEN + t0 + wv * 32] == 0) continue;

        const int r0 = row0 + wv * 32;
        const float* xr0 = x + (size_t)(r0 + lr) * D_IN;
        const float* xr1 = x + (size_t)(r0 + 16 + lr) * D_IN;

        f32x4 acc0[NCT], acc1[NCT];
#pragma unroll
        for (int i = 0; i < NCT; ++i) {
            acc0[i] = (f32x4){0.f, 0.f, 0.f, 0.f};
            acc1[i] = (f32x4){0.f, 0.f, 0.f, 0.f};
        }

        for (int ks = 0; ks < KSTEPS; ++ks) {
            const int k0 = ks * 32 + kch;
            float4 p0 = *(const float4*)(xr0 + k0);
            float4 p1 = *(const float4*)(xr0 + k0 + 4);
            float4 q0 = *(const float4*)(xr1 + k0);
            float4 q1 = *(const float4*)(xr1 + k0 + 4);

            uint4 h0, l0, h1, l1;
            pack2(p0.x, p0.y, h0.x, l0.x); pack2(p0.z, p0.w, h0.y, l0.y);
            pack2(p1.x, p1.y, h0.z, l0.z); pack2(p1.z, p1.w, h0.w, l0.w);
            pack2(q0.x, q0.y, h1.x, l1.x); pack2(q0.z, q0.w, h1.y, l1.y);
            pack2(q1.x, q1.y, h1.z, l1.z); pack2(q1.z, q1.w, h1.w, l1.w);

            s16x8 A0h = *(s16x8*)&h0, A0l = *(s16x8*)&l0;
            s16x8 A1h = *(s16x8*)&h1, A1l = *(s16x8*)&l1;

            const ushort* wph = g_Wh + (size_t)lr * D_IN + k0;
            const ushort* wpl = g_Wl + (size_t)lr * D_IN + k0;
#pragma unroll
            for (int ct = 0; ct < NCT; ++ct) {
                s16x8 Bh = *(const s16x8*)(wph + (size_t)ct * 16 * D_IN);
                s16x8 Bl = *(const s16x8*)(wpl + (size_t)ct * 16 * D_IN);
                acc0[ct] = __builtin_amdgcn_mfma_f32_16x16x32_bf16(A0h, Bh, acc0[ct], 0, 0, 0);
                acc0[ct] = __builtin_amdgcn_mfma_f32_16x16x32_bf16(A0l, Bh, acc0[ct], 0, 0, 0);
                acc0[ct] = __builtin_amdgcn_mfma_f32_16x16x32_bf16(A0h, Bl, acc0[ct], 0, 0, 0);
                acc1[ct] = __builtin_amdgcn_mfma_f32_16x16x32_bf16(A1h, Bh, acc1[ct], 0, 0, 0);
                acc1[ct] = __builtin_amdgcn_mfma_f32_16x16x32_bf16(A1l, Bh, acc1[ct], 0, 0, 0);
                acc1[ct] = __builtin_amdgcn_mfma_f32_16x16x32_bf16(A1h, Bl, acc1[ct], 0, 0, 0);
            }
        }

        const int orow = r0 + (lane >> 4) * 4;
        const int ocol = lane & 15;
#pragma unroll
        for (int ct = 0; ct < NCT; ++ct) {
            const int col = ct * 16 + ocol;
            if (col < G4) {
#pragma unroll
                for (int e = 0; e < 4; ++e) {
                    xg[(size_t)(orow + e) * G4 + col]      = acc0[ct][e];
                    xg[(size_t)(orow + 16 + e) * G4 + col] = acc1[ct][e];
                }
            }
        }
    }
}

// ---------------------------------------------------------------------------
// Kernel 2: LSTM scan, ONE WAVE per batch (64 threads, 256 blocks).
// Lane l (<50) owns h-dim l: holds W_hh rows {l, 50+l, 100+l, 150+l} in
// 200 VGPRs, c and h in registers. h[j] broadcast via v_readlane (unrolled
// j -> SGPR-operand FMAs). No LDS, no barriers: step cost is pure VALU issue
// (~560 cyc) vs ~1090 cyc for the old 4-wave barrier/LDS version.
// xg loads 2-step software-prefetched (2 named sets, loop unrolled by 2).
// ---------------------------------------------------------------------------
__global__ __launch_bounds__(64) void lstm_scan(
    const float* __restrict__ xg, const int* __restrict__ mask,
    const float* __restrict__ W_hh, const float* __restrict__ b_ih,
    const float* __restrict__ b_hh, const float* __restrict__ W_cls,
    const float* __restrict__ b_cls, float* __restrict__ out)
{
    const int b = blockIdx.x;
    const int l = threadIdx.x;

    int s = 0;
#pragma unroll
    for (int k = 0; k < 8; ++k) s += mask[b * S_LEN + l + 64 * k];
#pragma unroll
    for (int off = 1; off < 64; off <<= 1) s += __shfl_xor(s, off, 64);
    const int len = s;   // >= 1 by construction

    const bool act = (l < H_DIM);
    float wi[H_DIM], wf[H_DIM], wg[H_DIM], wo[H_DIM];
#pragma unroll
    for (int j = 0; j < H_DIM; ++j) {
        wi[j] = act ? W_hh[(size_t)l * H_DIM + j]           : 0.f;
        wf[j] = act ? W_hh[(size_t)(50 + l) * H_DIM + j]    : 0.f;
        wg[j] = act ? W_hh[(size_t)(100 + l) * H_DIM + j]   : 0.f;
        wo[j] = act ? W_hh[(size_t)(150 + l) * H_DIM + j]   : 0.f;
    }
    const float bi = act ? b_ih[l]       + b_hh[l]       : 0.f;
    const float bf = act ? b_ih[50 + l]  + b_hh[50 + l]  : 0.f;
    const float bg = act ? b_ih[100 + l] + b_hh[100 + l] : 0.f;
    const float bo = act ? b_ih[150 + l] + b_hh[150 + l] : 0.f;

    float h = 0.f, c = 0.f;
    const float* xgb = xg + (size_t)b * S_LEN * G4;

    float xiA = 0.f, xfA = 0.f, xqA = 0.f, xoA = 0.f;
    float xiB = 0.f, xfB = 0.f, xqB = 0.f, xoB = 0.f;
    if (act) {
        xiA = xgb[l]; xfA = xgb[50 + l]; xqA = xgb[100 + l]; xoA = xgb[150 + l];
        if (len > 1) {
            xiB = xgb[G4 + l]; xfB = xgb[G4 + 50 + l];
            xqB = xgb[G4 + 100 + l]; xoB = xgb[G4 + 150 + l];
        }
    }

    auto step = [&](int t, float& xi, float& xf, float& xq, float& xo) {
        float ai = xi + bi, af = xf + bf, ag = xq + bg, ao = xo + bo;
        if (act && t + 2 < len) {            // prefetch t+2 into this set
            const float* p = xgb + (size_t)(t + 2) * G4 + l;
            xi = p[0]; xf = p[50]; xq = p[100]; xo = p[150];
        }
#pragma unroll
        for (int j = 0; j < H_DIM; ++j) {
            float hj = __uint_as_float(
                (unsigned)__builtin_amdgcn_readlane(__float_as_uint(h), j));
            ai += hj * wi[j]; af += hj * wf[j];
            ag += hj * wg[j]; ao += hj * wo[j];
        }
        float ig = fsigmoid(ai), fg = fsigmoid(af);
        float gg = ftanh(ag),    og = fsigmoid(ao);
        c = fg * c + ig * gg;
        h = og * ftanh(c);
    };

    for (int t = 0; t < len; t += 2) {
        step(t, xiA, xfA, xqA, xoA);
        if (t + 1 < len) step(t + 1, xiB, xfB, xqB, xoB);
    }

    float p0 = act ? h * W_cls[l]      : 0.f;
    float p1 = act ? h * W_cls[50 + l] : 0.f;
#pragma unroll
    for (int off = 1; off < 64; off <<= 1) {
        p0 += __shfl_xor(p0, off, 64);
        p1 += __shfl_xor(p1, off, 64);
    }
    if (l == 0) {
        out[2 * b]     = p0 + b_cls[0];
        out[2 * b + 1] = p1 + b_cls[1];
    }
}

extern "C" void kernel_launch(void* const* d_in, const int* in_sizes, int n_in,
                              void* d_out, int out_size, void* d_ws, size_t ws_size,
                              hipStream_t stream) {
    const float* x     = (const float*)d_in[0];
    const int*   mask  = (const int*)  d_in[1];
    const float* W_ih  = (const float*)d_in[2];
    const float* W_hh  = (const float*)d_in[3];
    const float* b_ih  = (const float*)d_in[4];
    const float* b_hh  = (const float*)d_in[5];
    const float* W_cls = (const float*)d_in[6];
    const float* b_cls = (const float*)d_in[7];
    float* out = (float*)d_out;
    float* xg  = (float*)d_ws;   // 256*512*200*4 = 104.9 MB (fits: ws held xg in R1/R2)

    hipLaunchKernelGGL(prep_w, dim3((NPAD * D_IN + 255) / 256), dim3(256), 0, stream, W_ih);
    hipLaunchKernelGGL(gemm_xg, dim3(512), dim3(256), 0, stream, x, mask, xg);
    hipLaunchKernelGGL(lstm_scan, dim3(256), dim3(64), 0, stream,
                       xg, mask, W_hh, b_ih, b_hh, W_cls, b_cls, out);
}

// Round 4
// 688.905 us; speedup vs baseline: 1.1966x; 1.1966x over previous
//
#include <hip/hip_runtime.h>
#include <math.h>

#define S_LEN 512
#define D_IN  768
#define H_DIM 50
#define G4    200
#define NPAD  208      // 13 * 16
#define BROWS 128
#define NTILES 1024    // (256*512)/128
#define KSTEPS 24      // 768/32

typedef float f32x4 __attribute__((ext_vector_type(4)));
typedef short s16x8 __attribute__((ext_vector_type(8)));

__device__ ushort g_Wh[NPAD * D_IN];
__device__ ushort g_Wl[NPAD * D_IN];
__device__ int    g_counter;

__device__ __forceinline__ float fsigmoid(float x) {
    return 1.0f / (1.0f + __expf(-x));
}
__device__ __forceinline__ float ftanh(float x) {
    float ax = fabsf(x);
    float e  = __expf(-2.0f * ax);
    float t  = (1.0f - e) / (1.0f + e);
    return copysignf(t, x);
}

__global__ void prep_w(const float* __restrict__ W) {
    int idx = blockIdx.x * 256 + threadIdx.x;
    if (idx == 0) g_counter = 0;
    if (idx >= NPAD * D_IN) return;
    int n = idx / D_IN, k = idx - n * D_IN;
    float v = (n < G4) ? W[n * D_IN + k] : 0.f;
    unsigned u = __float_as_uint(v);
    ushort hi = (ushort)(u >> 16);
    float  hv = __uint_as_float((unsigned)hi << 16);
    float  d  = v - hv;
    g_Wh[idx] = hi;
    g_Wl[idx] = (ushort)(__float_as_uint(d) >> 16);
}

__device__ __forceinline__ void pack2(float f0, float f1, unsigned& h, unsigned& l) {
    unsigned u0 = __float_as_uint(f0), u1 = __float_as_uint(f1);
    h = (u0 >> 16) | (u1 & 0xffff0000u);
    float d0 = f0 - __uint_as_float(u0 & 0xffff0000u);
    float d1 = f1 - __uint_as_float(u1 & 0xffff0000u);
    l = (__float_as_uint(d0) >> 16) | (__float_as_uint(d1) & 0xffff0000u);
}

// one ct-range pass over the full K for a 32-row strip: acc = CTN f32x4 pairs
template<int CT0, int CTN>
__device__ __forceinline__ void gemm_pass(
    const float* xr0, const float* xr1, int lr, int kch,
    int r0, float* __restrict__ xg)
{
    f32x4 acc0[CTN], acc1[CTN];
#pragma unroll
    for (int i = 0; i < CTN; ++i) {
        acc0[i] = (f32x4){0.f, 0.f, 0.f, 0.f};
        acc1[i] = (f32x4){0.f, 0.f, 0.f, 0.f};
    }
    const ushort* wph = g_Wh + (size_t)lr * D_IN + kch + (size_t)CT0 * 16 * D_IN;
    const ushort* wpl = g_Wl + (size_t)lr * D_IN + kch + (size_t)CT0 * 16 * D_IN;

    for (int ks = 0; ks < KSTEPS; ++ks) {
        const int k0 = ks * 32 + kch;
        float4 p0 = *(const float4*)(xr0 + k0);
        float4 p1 = *(const float4*)(xr0 + k0 + 4);
        float4 q0 = *(const float4*)(xr1 + k0);
        float4 q1 = *(const float4*)(xr1 + k0 + 4);

        uint4 h0, l0, h1, l1;
        pack2(p0.x, p0.y, h0.x, l0.x); pack2(p0.z, p0.w, h0.y, l0.y);
        pack2(p1.x, p1.y, h0.z, l0.z); pack2(p1.z, p1.w, h0.w, l0.w);
        pack2(q0.x, q0.y, h1.x, l1.x); pack2(q0.z, q0.w, h1.y, l1.y);
        pack2(q1.x, q1.y, h1.z, l1.z); pack2(q1.z, q1.w, h1.w, l1.w);

        s16x8 A0h = *(s16x8*)&h0, A0l = *(s16x8*)&l0;
        s16x8 A1h = *(s16x8*)&h1, A1l = *(s16x8*)&l1;

        const ushort* bh = wph + (size_t)ks * 32;
        const ushort* bl = wpl + (size_t)ks * 32;
#pragma unroll
        for (int i = 0; i < CTN; ++i) {
            s16x8 Bh = *(const s16x8*)(bh + (size_t)i * 16 * D_IN);
            s16x8 Bl = *(const s16x8*)(bl + (size_t)i * 16 * D_IN);
            acc0[i] = __builtin_amdgcn_mfma_f32_16x16x32_bf16(A0h, Bh, acc0[i], 0, 0, 0);
            acc0[i] = __builtin_amdgcn_mfma_f32_16x16x32_bf16(A0l, Bh, acc0[i], 0, 0, 0);
            acc0[i] = __builtin_amdgcn_mfma_f32_16x16x32_bf16(A0h, Bl, acc0[i], 0, 0, 0);
            acc1[i] = __builtin_amdgcn_mfma_f32_16x16x32_bf16(A1h, Bh, acc1[i], 0, 0, 0);
            acc1[i] = __builtin_amdgcn_mfma_f32_16x16x32_bf16(A1l, Bh, acc1[i], 0, 0, 0);
            acc1[i] = __builtin_amdgcn_mfma_f32_16x16x32_bf16(A1h, Bl, acc1[i], 0, 0, 0);
        }
    }
    const int lane = (lr | ((kch >> 3) << 4));           // reconstruct lane
    const int orow = r0 + (lane >> 4) * 4;
    const int ocol = lane & 15;
#pragma unroll
    for (int i = 0; i < CTN; ++i) {
        const int col = (CT0 + i) * 16 + ocol;
        if (col < G4) {
#pragma unroll
            for (int e = 0; e < 4; ++e) {
                xg[(size_t)(orow + e) * G4 + col]      = acc0[i][e];
                xg[(size_t)(orow + 16 + e) * G4 + col] = acc1[i][e];
            }
        }
    }
}

// xg = x @ W_ih^T, split-bf16 MFMA (AhBh+AlBh+AhBl), no LDS staging.
// 2 col-half passes/strip keep acc regs at 28 -> VGPR<=128 -> 4 blocks/CU.
__global__ __launch_bounds__(256, 4) void gemm_xg(
    const float* __restrict__ x, const int* __restrict__ mask,
    float* __restrict__ xg)
{
    __shared__ int tile_sh;
    const int tid  = threadIdx.x;
    const int wv   = tid >> 6;
    const int lane = tid & 63;
    const int lr   = lane & 15;
    const int kch  = (lane >> 4) * 8;

    for (;;) {
        if (tid == 0) tile_sh = atomicAdd(&g_counter, 1);
        __syncthreads();
        const int tile = tile_sh;
        __syncthreads();
        if (tile >= NTILES) return;

        const int row0 = tile * BROWS;
        const int b    = row0 >> 9;
        const int t0   = row0 & (S_LEN - 1);
        if (mask[b * S_LEN + t0 + wv * 32] == 0) continue;  // strip fully masked

        const int r0 = row0 + wv * 32;
        const float* xr0 = x + (size_t)(r0 + lr) * D_IN;
        const float* xr1 = x + (size_t)(r0 + 16 + lr) * D_IN;

        gemm_pass<0, 7>(xr0, xr1, lr, kch, r0, xg);
        gemm_pass<7, 6>(xr0, xr1, lr, kch, r0, xg);
    }
}

// ---------------------------------------------------------------------------
// LSTM scan: 1 block (4 waves) per batch. Wave w = gate-type w; lane l<50
// holds W_hh row 50w+l in 50 VGPRs (no spill). h is replicated in every
// wave's registers -> matvec broadcast via in-wave readlane (no LDS, no
// barrier). Gates cross waves once/step through double-buffered LDS with a
// single barrier (buffer parity + pre-barrier lgkmcnt drain => race-free).
// ---------------------------------------------------------------------------
__global__ __launch_bounds__(256) void lstm_scan(
    const float* __restrict__ xg, const int* __restrict__ mask,
    const float* __restrict__ W_hh, const float* __restrict__ b_ih,
    const float* __restrict__ b_hh, const float* __restrict__ W_cls,
    const float* __restrict__ b_cls, float* __restrict__ out)
{
    const int b    = blockIdx.x;
    const int tid  = threadIdx.x;
    const int lane = tid & 63;
    const int wv   = tid >> 6;

    __shared__ int   red[4];
    __shared__ int   len_sh;
    __shared__ float gbuf[2][G4];

    int s = mask[b * S_LEN + tid] + mask[b * S_LEN + tid + 256];
#pragma unroll
    for (int off = 32; off > 0; off >>= 1) s += __shfl_down(s, off, 64);
    if (lane == 0) red[wv] = s;
    __syncthreads();
    if (tid == 0) len_sh = red[0] + red[1] + red[2] + red[3];
    __syncthreads();
    const int len = len_sh;

    const bool act = (lane < H_DIM);
    const int  row = wv * H_DIM + lane;          // gate row for this thread

    float w[H_DIM];
#pragma unroll
    for (int j = 0; j < H_DIM; ++j) w[j] = act ? W_hh[(size_t)row * H_DIM + j] : 0.f;
    const float bias = act ? b_ih[row] + b_hh[row] : 0.f;

    float h = 0.f, c = 0.f;
    const float* xgb = xg + (size_t)b * S_LEN * G4;

    float xvA = act ? xgb[row] : 0.f;
    float xvB = (act && len > 1) ? xgb[G4 + row] : 0.f;

#define RL(j) __uint_as_float((unsigned)__builtin_amdgcn_readlane(__float_as_uint(h), (j)))

    auto step = [&](int t, float& xv) {
        float s0 = 0.f, s1 = 0.f, s2 = 0.f, s3 = 0.f;
#pragma unroll
        for (int q = 0; q < 12; ++q) {
            s0 += RL(4*q+0) * w[4*q+0];
            s1 += RL(4*q+1) * w[4*q+1];
            s2 += RL(4*q+2) * w[4*q+2];
            s3 += RL(4*q+3) * w[4*q+3];
        }
        s0 += RL(48) * w[48];
        s1 += RL(49) * w[49];
        float a = xv + bias + (s0 + s1) + (s2 + s3);
        if (act && t + 2 < len) xv = xgb[(size_t)(t + 2) * G4 + row];  // prefetch
        float gv = (wv == 2) ? ftanh(a) : fsigmoid(a);
        if (act) gbuf[t & 1][row] = gv;
        __syncthreads();
        if (act) {
            float ig = gbuf[t & 1][lane];
            float fg = gbuf[t & 1][H_DIM + lane];
            float gg = gbuf[t & 1][2 * H_DIM + lane];
            float og = gbuf[t & 1][3 * H_DIM + lane];
            c = fg * c + ig * gg;
            h = og * ftanh(c);           // replicated in all 4 waves
        }
    };

    for (int t = 0; t < len; t += 2) {
        step(t, xvA);
        if (t + 1 < len) step(t + 1, xvB);
    }
#undef RL

    if (wv == 0) {
        float p0 = act ? h * W_cls[lane] : 0.f;
        float p1 = act ? h * W_cls[H_DIM + lane] : 0.f;
#pragma unroll
        for (int off = 1; off < 64; off <<= 1) {
            p0 += __shfl_xor(p0, off, 64);
            p1 += __shfl_xor(p1, off, 64);
        }
        if (lane == 0) {
            out[2 * b]     = p0 + b_cls[0];
            out[2 * b + 1] = p1 + b_cls[1];
        }
    }
}

extern "C" void kernel_launch(void* const* d_in, const int* in_sizes, int n_in,
                              void* d_out, int out_size, void* d_ws, size_t ws_size,
                              hipStream_t stream) {
    const float* x     = (const float*)d_in[0];
    const int*   mask  = (const int*)  d_in[1];
    const float* W_ih  = (const float*)d_in[2];
    const float* W_hh  = (const float*)d_in[3];
    const float* b_ih  = (const float*)d_in[4];
    const float* b_hh  = (const float*)d_in[5];
    const float* W_cls = (const float*)d_in[6];
    const float* b_cls = (const float*)d_in[7];
    float* out = (float*)d_out;
    float* xg  = (float*)d_ws;   // 104.9 MB

    hipLaunchKernelGGL(prep_w, dim3((NPAD * D_IN + 255) / 256), dim3(256), 0, stream, W_ih);
    hipLaunchKernelGGL(gemm_xg, dim3(1024), dim3(256), 0, stream, x, mask, xg);
    hipLaunchKernelGGL(lstm_scan, dim3(256), dim3(256), 0, stream,
                       xg, mask, W_hh, b_ih, b_hh, W_cls, b_cls, out);
}

// Round 6
// 393.101 us; speedup vs baseline: 2.0970x; 1.7525x over previous
//
#include <hip/hip_runtime.h>
#include <math.h>

#define S_LEN 512
#define D_IN  768
#define H_DIM 50
#define G4    200
#define NCT   13
#define BROWS 128
#define NTILES 1024      // (256*512)/128
#define KSTEPS 24        // 768/32
#define FR_KS  13312     // ushorts per K-step of frag-packed W (26,624 B)

typedef float   f32x4 __attribute__((ext_vector_type(4)));
typedef short   s16x8 __attribute__((ext_vector_type(8)));
typedef _Float16 f16x2 __attribute__((ext_vector_type(2)));

__device__ ushort g_Wf[KSTEPS * FR_KS];   // [ks][ct][half][lane][8]
__device__ int    g_counter;

__device__ __forceinline__ float fsigmoid(float x) {
    return 1.0f / (1.0f + __expf(-x));
}
__device__ __forceinline__ float ftanh(float x) {
    float ax = fabsf(x);
    float e  = __expf(-2.0f * ax);
    float t  = (1.0f - e) / (1.0f + e);
    return copysignf(t, x);
}

// ---------------------------------------------------------------------------
// prep: pack W_ih into MFMA-frag-linear bf16 hi/lo: g_Wf[ks][ct][half][lane][8]
// frag element j of lane l = W[ct*16+(l&15)][ks*32+(l>>4)*8+j] (hi or lo-residual).
// B-staging becomes a pure linear copy (global_load_lds-compatible) and
// B-frag reads single conflict-free ds_read_b128 at lane*16 + imm.
// ---------------------------------------------------------------------------
__global__ void prep_w(const float* __restrict__ W) {
    int f = blockIdx.x * 256 + threadIdx.x;          // frag id
    if (f == 0) g_counter = 0;
    if (f >= KSTEPS * 26 * 64) return;               // 39936 frags
    const int l  = f & 63;
    const int g  = (f >> 6) % 26;
    const int ks = (f >> 6) / 26;
    const int ct = g >> 1, hf = g & 1;
    const int n  = ct * 16 + (l & 15);
    const int k0 = ks * 32 + (l >> 4) * 8;
    ushort v[8] __attribute__((aligned(16)));
#pragma unroll
    for (int j = 0; j < 8; ++j) v[j] = 0;
    if (n < G4) {
        const float* wp = &W[(size_t)n * D_IN + k0];
#pragma unroll
        for (int j = 0; j < 8; ++j) {
            float xv = wp[j];
            unsigned u = __float_as_uint(xv);
            if (hf == 0) v[j] = (ushort)(u >> 16);
            else {
                float d = xv - __uint_as_float(u & 0xffff0000u);
                v[j] = (ushort)(__float_as_uint(d) >> 16);
            }
        }
    }
    *(uint4*)&g_Wf[(size_t)f * 8] = *(const uint4*)v;
}

__device__ __forceinline__ void pack2(float f0, float f1, unsigned& h, unsigned& l) {
    unsigned u0 = __float_as_uint(f0), u1 = __float_as_uint(f1);
    h = (u0 >> 16) | (u1 & 0xffff0000u);
    float d0 = f0 - __uint_as_float(u0 & 0xffff0000u);
    float d1 = f1 - __uint_as_float(u1 & 0xffff0000u);
    l = (__float_as_uint(d0) >> 16) | (__float_as_uint(d1) & 0xffff0000u);
}

// async-stage one K-step of packed W into LDS (26,624 B). Wave wv covers its
// 1KB chunks; LDS dest is wave-uniform base (HW adds lane*16).
__device__ __forceinline__ void stage_b(int ks, ushort* dst, int wv, int lane) {
    const ushort* gb = g_Wf + (size_t)ks * FR_KS;
#pragma unroll
    for (int i = 0; i < 7; ++i) {
        const int c0 = i * 2048 + wv * 512;          // ushort units
        if (c0 < FR_KS) {
#if __has_builtin(__builtin_amdgcn_global_load_lds)
            __builtin_amdgcn_global_load_lds(
                (const __attribute__((address_space(1))) unsigned int*)(gb + c0 + lane * 8),
                (__attribute__((address_space(3))) unsigned int*)(dst + c0),
                16, 0, 0);
#else
            *(uint4*)(dst + c0 + (size_t)lane * 8) = *(const uint4*)(gb + c0 + (size_t)lane * 8);
#endif
        }
    }
}

// ---------------------------------------------------------------------------
// xg = x @ W_ih^T, split-bf16 MFMA (AhBh + AlBh + AhBl).
// B: LDS double-buffered via async global_load_lds from frag-linear g_Wf;
// one barrier per K-step. A: direct global float4 loads, 1-step register
// prefetch, packed in-reg. Persistent blocks on an atomic queue; dead
// 128-row tiles skipped wholesale, dead 32-row strips skip compute.
// ---------------------------------------------------------------------------
__global__ __launch_bounds__(256, 2) void gemm_xg(
    const float* __restrict__ x, const int* __restrict__ mask,
    float* __restrict__ xg)
{
    __shared__ ushort Bs[2][FR_KS];                  // 53,248 B
    __shared__ int tile_sh;
    const int tid  = threadIdx.x;
    const int wv   = tid >> 6;
    const int lane = tid & 63;
    const int lr   = lane & 15;
    const int kch  = (lane >> 4) * 8;

    for (;;) {
        if (tid == 0) tile_sh = atomicAdd(&g_counter, 1);
        __syncthreads();
        const int tile = tile_sh;
        __syncthreads();
        if (tile >= NTILES) return;

        const int row0 = tile * BROWS;
        const int b    = row0 >> 9;
        const int t0   = row0 & (S_LEN - 1);
        if (mask[b * S_LEN + t0] == 0) continue;     // whole tile past length[b]
        const bool live = mask[b * S_LEN + t0 + wv * 32] != 0;

        const int r0 = row0 + wv * 32;
        const float* xr0 = x + (size_t)(r0 + lr) * D_IN;
        const float* xr1 = xr0 + (size_t)16 * D_IN;

        f32x4 acc0[NCT], acc1[NCT];
#pragma unroll
        for (int i = 0; i < NCT; ++i) {
            acc0[i] = (f32x4){0.f, 0.f, 0.f, 0.f};
            acc1[i] = (f32x4){0.f, 0.f, 0.f, 0.f};
        }
        float4 ac0 = {0,0,0,0}, ac1 = {0,0,0,0}, ac2 = {0,0,0,0}, ac3 = {0,0,0,0};
        float4 an0 = {0,0,0,0}, an1 = {0,0,0,0}, an2 = {0,0,0,0}, an3 = {0,0,0,0};

        stage_b(0, Bs[0], wv, lane);
        if (live) {
            ac0 = *(const float4*)(xr0 + kch);
            ac1 = *(const float4*)(xr0 + kch + 4);
            ac2 = *(const float4*)(xr1 + kch);
            ac3 = *(const float4*)(xr1 + kch + 4);
        }
        __syncthreads();                             // Bs[0] staged & drained

        for (int ks = 0; ks < KSTEPS; ++ks) {
            if (ks < KSTEPS - 1) {
                stage_b(ks + 1, Bs[(ks + 1) & 1], wv, lane);
                if (live) {
                    const int k1 = (ks + 1) * 32 + kch;
                    an0 = *(const float4*)(xr0 + k1);
                    an1 = *(const float4*)(xr0 + k1 + 4);
                    an2 = *(const float4*)(xr1 + k1);
                    an3 = *(const float4*)(xr1 + k1 + 4);
                }
            }
            if (live) {
                uint4 h0, l0, h1, l1;
                pack2(ac0.x, ac0.y, h0.x, l0.x); pack2(ac0.z, ac0.w, h0.y, l0.y);
                pack2(ac1.x, ac1.y, h0.z, l0.z); pack2(ac1.z, ac1.w, h0.w, l0.w);
                pack2(ac2.x, ac2.y, h1.x, l1.x); pack2(ac2.z, ac2.w, h1.y, l1.y);
                pack2(ac3.x, ac3.y, h1.z, l1.z); pack2(ac3.z, ac3.w, h1.w, l1.w);
                s16x8 A0h = *(s16x8*)&h0, A0l = *(s16x8*)&l0;
                s16x8 A1h = *(s16x8*)&h1, A1l = *(s16x8*)&l1;
                const ushort* bp = &Bs[ks & 1][lane * 8];
#pragma unroll
                for (int ct = 0; ct < NCT; ++ct) {
                    s16x8 Bh = *(const s16x8*)(bp + ct * 1024);
                    s16x8 Bl = *(const s16x8*)(bp + ct * 1024 + 512);
                    acc0[ct] = __builtin_amdgcn_mfma_f32_16x16x32_bf16(A0h, Bh, acc0[ct], 0, 0, 0);
                    acc0[ct] = __builtin_amdgcn_mfma_f32_16x16x32_bf16(A0l, Bh, acc0[ct], 0, 0, 0);
                    acc0[ct] = __builtin_amdgcn_mfma_f32_16x16x32_bf16(A0h, Bl, acc0[ct], 0, 0, 0);
                    acc1[ct] = __builtin_amdgcn_mfma_f32_16x16x32_bf16(A1h, Bh, acc1[ct], 0, 0, 0);
                    acc1[ct] = __builtin_amdgcn_mfma_f32_16x16x32_bf16(A1l, Bh, acc1[ct], 0, 0, 0);
                    acc1[ct] = __builtin_amdgcn_mfma_f32_16x16x32_bf16(A1h, Bl, acc1[ct], 0, 0, 0);
                }
            }
            ac0 = an0; ac1 = an1; ac2 = an2; ac3 = an3;
            __syncthreads();                         // readers done; stage(ks+1) drained
        }

        if (live) {
            const int orow = r0 + (lane >> 4) * 4;
            const int ocol = lane & 15;
#pragma unroll
            for (int ct = 0; ct < NCT; ++ct) {
                const int col = ct * 16 + ocol;
                if (col < G4) {
#pragma unroll
                    for (int e = 0; e < 4; ++e) {
                        xg[(size_t)(orow + e) * G4 + col]      = acc0[ct][e];
                        xg[(size_t)(orow + 16 + e) * G4 + col] = acc1[ct][e];
                    }
                }
            }
        }
    }
}

// ---------------------------------------------------------------------------
// LSTM scan: ONE WAVE per batch, ZERO barriers (prefetch loads are never
// drained by syncs). Lane l<50 owns h-dim l and the 4 gate rows {l,50+l,
// 100+l,150+l} of W_hh as 100 half2 VGPRs. Matvec = 25 readlane-broadcast
// h-pairs x 4 gates of v_dot2_f32_f16 (f32 accumulate). h-pairs built with
// 2 ds_bpermute + cvt_pkrtz. xg loads 4-deep software-prefetched.
// ---------------------------------------------------------------------------
__global__ __launch_bounds__(64, 1) void lstm_scan(
    const float* __restrict__ xgp, const int* __restrict__ mask,
    const float* __restrict__ W_hh, const float* __restrict__ b_ih,
    const float* __restrict__ b_hh, const float* __restrict__ W_cls,
    const float* __restrict__ b_cls, float* __restrict__ out)
{
    const int b = blockIdx.x;
    const int l = threadIdx.x;

    int s = 0;
#pragma unroll
    for (int k = 0; k < 8; ++k) s += mask[b * S_LEN + l + 64 * k];
#pragma unroll
    for (int off = 1; off < 64; off <<= 1) s += __shfl_xor(s, off, 64);
    const int len = s;                               // >= 1

    const bool act = (l < H_DIM);
    f16x2 wi2[25], wf2[25], wg2[25], wo2[25];
#pragma unroll
    for (int q = 0; q < 25; ++q) {
        if (act) {
            const float* p0 = &W_hh[(size_t)l * H_DIM + 2 * q];
            const float* p1 = &W_hh[(size_t)(50 + l) * H_DIM + 2 * q];
            const float* p2 = &W_hh[(size_t)(100 + l) * H_DIM + 2 * q];
            const float* p3 = &W_hh[(size_t)(150 + l) * H_DIM + 2 * q];
            wi2[q] = (f16x2){(_Float16)p0[0], (_Float16)p0[1]};
            wf2[q] = (f16x2){(_Float16)p1[0], (_Float16)p1[1]};
            wg2[q] = (f16x2){(_Float16)p2[0], (_Float16)p2[1]};
            wo2[q] = (f16x2){(_Float16)p3[0], (_Float16)p3[1]};
        } else {
            wi2[q] = (f16x2){0, 0}; wf2[q] = (f16x2){0, 0};
            wg2[q] = (f16x2){0, 0}; wo2[q] = (f16x2){0, 0};
        }
    }
    const float bi = act ? b_ih[l]           + b_hh[l]           : 0.f;
    const float bf = act ? b_ih[50 + l]      + b_hh[50 + l]      : 0.f;
    const float bg = act ? b_ih[100 + l]     + b_hh[100 + l]     : 0.f;
    const float bo = act ? b_ih[150 + l]     + b_hh[150 + l]     : 0.f;

    float h = 0.f, c = 0.f;
    const float* xgb = xgp + (size_t)b * S_LEN * G4;

    auto ld = [&](int t, float& xi, float& xf, float& xq, float& xo) {
        if (act && t < len) {
            const float* pp = xgb + (size_t)t * G4 + l;
            xi = pp[0]; xf = pp[50]; xq = pp[100]; xo = pp[150];
        }
    };
    float xiA=0,xfA=0,xqA=0,xoA=0, xiB=0,xfB=0,xqB=0,xoB=0;
    float xiC=0,xfC=0,xqC=0,xoC=0, xiD=0,xfD=0,xqD=0,xoD=0;
    ld(0, xiA, xfA, xqA, xoA); ld(1, xiB, xfB, xqB, xoB);
    ld(2, xiC, xfC, xqC, xoC); ld(3, xiD, xfD, xqD, xoD);

#if __has_builtin(__builtin_amdgcn_fdot2)
#define FDOT2(a, b, cc) __builtin_amdgcn_fdot2((a), (b), (cc), false)
#else
#define FDOT2(a, b, cc) ((cc) + (float)(a)[0] * (float)(b)[0] + (float)(a)[1] * (float)(b)[1])
#endif

    auto step = [&](int t, float& xi, float& xf, float& xq, float& xo) {
        // build this lane's h-pair (h[2l], h[2l+1]) then broadcast via readlane
        int pa = __builtin_amdgcn_ds_bpermute(8 * l,     __float_as_int(h));
        int pb = __builtin_amdgcn_ds_bpermute(8 * l + 4, __float_as_int(h));
#if __has_builtin(__builtin_amdgcn_cvt_pkrtz)
        f16x2 hp = __builtin_bit_cast(f16x2,
            __builtin_amdgcn_cvt_pkrtz(__int_as_float(pa), __int_as_float(pb)));
#else
        f16x2 hp = (f16x2){(_Float16)__int_as_float(pa), (_Float16)__int_as_float(pb)};
#endif
        unsigned hu = __builtin_bit_cast(unsigned, hp);

        float ai = xi + bi, af = xf + bf, aq = xq + bg, ao = xo + bo;
        ld(t + 4, xi, xf, xq, xo);                   // prefetch into this set
#pragma unroll
        for (int q = 0; q < 25; ++q) {
            unsigned r = (unsigned)__builtin_amdgcn_readlane((int)hu, q);
            f16x2 hq = __builtin_bit_cast(f16x2, r);
            ai = FDOT2(hq, wi2[q], ai);
            af = FDOT2(hq, wf2[q], af);
            aq = FDOT2(hq, wg2[q], aq);
            ao = FDOT2(hq, wo2[q], ao);
        }
        float ig = fsigmoid(ai), fg = fsigmoid(af);
        float gg = ftanh(aq),    og = fsigmoid(ao);
        if (act) {
            c = fg * c + ig * gg;
            h = og * ftanh(c);
        }
    };

    int t = 0;
    while (t < len) {
        step(t, xiA, xfA, xqA, xoA); ++t; if (t >= len) break;
        step(t, xiB, xfB, xqB, xoB); ++t; if (t >= len) break;
        step(t, xiC, xfC, xqC, xoC); ++t; if (t >= len) break;
        step(t, xiD, xfD, xqD, xoD); ++t;
    }
#undef FDOT2

    float p0 = act ? h * W_cls[l]          : 0.f;
    float p1 = act ? h * W_cls[H_DIM + l]  : 0.f;
#pragma unroll
    for (int off = 1; off < 64; off <<= 1) {
        p0 += __shfl_xor(p0, off, 64);
        p1 += __shfl_xor(p1, off, 64);
    }
    if (l == 0) {
        out[2 * b]     = p0 + b_cls[0];
        out[2 * b + 1] = p1 + b_cls[1];
    }
}

extern "C" void kernel_launch(void* const* d_in, const int* in_sizes, int n_in,
                              void* d_out, int out_size, void* d_ws, size_t ws_size,
                              hipStream_t stream) {
    const float* x     = (const float*)d_in[0];
    const int*   mask  = (const int*)  d_in[1];
    const float* W_ih  = (const float*)d_in[2];
    const float* W_hh  = (const float*)d_in[3];
    const float* b_ih  = (const float*)d_in[4];
    const float* b_hh  = (const float*)d_in[5];
    const float* W_cls = (const float*)d_in[6];
    const float* b_cls = (const float*)d_in[7];
    float* out = (float*)d_out;
    float* xg  = (float*)d_ws;                       // 104.9 MB

    hipLaunchKernelGGL(prep_w, dim3(156), dim3(256), 0, stream, W_ih);
    hipLaunchKernelGGL(gemm_xg, dim3(512), dim3(256), 0, stream, x, mask, xg);
    hipLaunchKernelGGL(lstm_scan, dim3(256), dim3(64), 0, stream,
                       xg, mask, W_hh, b_ih, b_hh, W_cls, b_cls, out);
}